// Round 9
// baseline (155.669 us; speedup 1.0000x reference)
//
#include <hip/hip_runtime.h>

#define N 12288
#define M (2 * N)          // keys (t_j) + queries (-s_i)
#define DIN 128
#define DOUT 64
#define NBIN 8192
#define BSHIFT 19          // 32 - log2(NBIN)
#define NCHUNK 384         // M / 64

// monotone float -> ordered u32 (order-preserving bit transform)
__device__ __forceinline__ unsigned f_ord(float x) {
    unsigned b = __float_as_uint(x);
    return (b & 0x80000000u) ? ~b : (b | 0x80000000u);
}
__device__ __forceinline__ float ord_f(unsigned u) {
    unsigned b = (u & 0x80000000u) ? (u & 0x7FFFFFFFu) : ~u;
    return __uint_as_float(b);
}
__device__ __forceinline__ int t_bin(float x) { return (int)(f_ord(x) >> BSHIFT); }

struct Args {
    const float *h, *W, *a;
    float *Wh, *s, *t, *tblkmax, *Thdr;
    unsigned long long *vals64;     // (ordered(val)<<32)|pi — unique total order
    float *tfin;
    int *idfin, *binstart;
    float2 *VU;                     // per-chunk column sums {v,u}
    float2 *sc;                     // per-chunk scalar sums {vs,us}
    float *out;
};

// ---------- K1: Wh = h@W, s, t, per-block max(t) (384 blocks x 128) ---------
__global__ __launch_bounds__(128) void k1_gemm(Args A) {
    __shared__ float4 sm4[3072];               // 48 KB: W 32K + h-tile 16K
    __shared__ float wmax[2];
    int tid = threadIdx.x, wave = tid >> 6, lane = tid & 63, blk = blockIdx.x;
    float4* Ws4 = sm4;                         // W[k][c4]  (2048)
    float4* hs4 = sm4 + 2048;                  // h[r][k4]  (1024: 32 rows)
    const float4* W4 = (const float4*)A.W;
    #pragma unroll
    for (int e = tid; e < 2048; e += 128) Ws4[e] = W4[e];
    int row0 = blk * 32;
    const float4* h4 = (const float4*)(A.h + (size_t)row0 * DIN);
    #pragma unroll
    for (int e = tid; e < 1024; e += 128) hs4[e] = h4[e];
    __syncthreads();
    int c0 = lane & 15, rq = lane >> 4;
    int rbase = wave * 16 + rq * 4;            // 2 waves cover 32 rows
    float4 acc[4];
    #pragma unroll
    for (int rr = 0; rr < 4; ++rr) acc[rr] = make_float4(0.f, 0.f, 0.f, 0.f);
    #pragma unroll 2
    for (int kk = 0; kk < 32; ++kk) {
        float4 w0 = Ws4[(4 * kk + 0) * 16 + c0];
        float4 w1 = Ws4[(4 * kk + 1) * 16 + c0];
        float4 w2 = Ws4[(4 * kk + 2) * 16 + c0];
        float4 w3 = Ws4[(4 * kk + 3) * 16 + c0];
        #pragma unroll
        for (int rr = 0; rr < 4; ++rr) {
            float4 hv = hs4[(rbase + rr) * 32 + kk];
            acc[rr].x = fmaf(hv.x, w0.x, acc[rr].x);
            acc[rr].y = fmaf(hv.x, w0.y, acc[rr].y);
            acc[rr].z = fmaf(hv.x, w0.z, acc[rr].z);
            acc[rr].w = fmaf(hv.x, w0.w, acc[rr].w);
            acc[rr].x = fmaf(hv.y, w1.x, acc[rr].x);
            acc[rr].y = fmaf(hv.y, w1.y, acc[rr].y);
            acc[rr].z = fmaf(hv.y, w1.z, acc[rr].z);
            acc[rr].w = fmaf(hv.y, w1.w, acc[rr].w);
            acc[rr].x = fmaf(hv.z, w2.x, acc[rr].x);
            acc[rr].y = fmaf(hv.z, w2.y, acc[rr].y);
            acc[rr].z = fmaf(hv.z, w2.z, acc[rr].z);
            acc[rr].w = fmaf(hv.z, w2.w, acc[rr].w);
            acc[rr].x = fmaf(hv.w, w3.x, acc[rr].x);
            acc[rr].y = fmaf(hv.w, w3.y, acc[rr].y);
            acc[rr].z = fmaf(hv.w, w3.z, acc[rr].z);
            acc[rr].w = fmaf(hv.w, w3.w, acc[rr].w);
        }
    }
    float4 a1 = ((const float4*)A.a)[c0];
    float4 a2 = ((const float4*)A.a)[16 + c0];
    float tmax = -3.4e38f;
    #pragma unroll
    for (int rr = 0; rr < 4; ++rr) {
        int row = row0 + rbase + rr;
        ((float4*)A.Wh)[(size_t)row * 16 + c0] = acc[rr];
        float sv = acc[rr].x * a1.x + acc[rr].y * a1.y + acc[rr].z * a1.z + acc[rr].w * a1.w;
        float tv = acc[rr].x * a2.x + acc[rr].y * a2.y + acc[rr].z * a2.z + acc[rr].w * a2.w;
        #pragma unroll
        for (int off = 8; off; off >>= 1) {     // reduce over 16-lane group
            sv += __shfl_xor(sv, off, 64);
            tv += __shfl_xor(tv, off, 64);
        }
        if (c0 == 0) { A.s[row] = sv; A.t[row] = tv; }
        tmax = fmaxf(tmax, tv);
    }
    tmax = fmaxf(tmax, __shfl_xor(tmax, 16, 64));
    tmax = fmaxf(tmax, __shfl_xor(tmax, 32, 64));
    if (lane == 0) wmax[wave] = tmax;
    __syncthreads();
    if (tid == 0) A.tblkmax[blk] = fmaxf(wmax[0], wmax[1]);
}

// ---------- K2: LDS hist + pre-hist + scan + T + packed-key scatter ----------
// 24 blocks x 1024; slice = 1024 items/block. Full histogram (and before-slice
// histogram) built redundantly in LDS -> no global atomics anywhere.
__global__ __launch_bounds__(1024) void k2_sort(Args A) {
    __shared__ int hist[NBIN];                  // 32 KB
    __shared__ int pre[NBIN];                   // 32 KB
    __shared__ int wtot[16];
    __shared__ float fmax_[16];
    int tid = threadIdx.x, lane = tid & 63, wave = tid >> 6, blk = blockIdx.x;
    #pragma unroll
    for (int e = tid; e < NBIN; e += 1024) { hist[e] = 0; pre[e] = 0; }
    __syncthreads();
    #pragma unroll 4
    for (int e = tid; e < M; e += 1024) {
        float v = (e < N) ? A.t[e] : -A.s[e - N];
        atomicAdd(&hist[t_bin(v)], 1);
    }
    int my0 = blk * 1024;
    #pragma unroll 4
    for (int e = tid; e < my0; e += 1024) {
        float v = (e < N) ? A.t[e] : -A.s[e - N];
        atomicAdd(&pre[t_bin(v)], 1);
    }
    __syncthreads();
    int b0 = tid * 8;
    int c8[8]; int sum = 0;
    #pragma unroll
    for (int g = 0; g < 8; ++g) { c8[g] = sum; sum += hist[b0 + g]; }
    int inc = sum;
    #pragma unroll
    for (int off = 1; off < 64; off <<= 1) {
        int nb = __shfl_up(inc, off, 64);
        if (lane >= off) inc += nb;
    }
    if (lane == 63) wtot[wave] = inc;
    __syncthreads();
    int wbase = 0;
    #pragma unroll
    for (int w = 0; w < 16; ++w) wbase += (w < wave) ? wtot[w] : 0;
    int tstart = wbase + inc - sum;
    #pragma unroll
    for (int g = 0; g < 8; ++g) {
        int bs = tstart + c8[g];
        hist[b0 + g] = bs;
        pre[b0 + g] += bs;
        A.binstart[b0 + g] = bs;                // benign duplicate across blocks
    }
    if (tid == 0 && blk == 0) A.binstart[NBIN] = M;
    float m = (tid < 384) ? A.tblkmax[tid] : -3.4e38f;
    #pragma unroll
    for (int off = 32; off; off >>= 1) m = fmaxf(m, __shfl_xor(m, off, 64));
    if (lane == 0) fmax_[wave] = m;
    __syncthreads();
    if (tid == 0) {
        float mm = fmax_[0];
        #pragma unroll
        for (int w = 1; w < 16; ++w) mm = fmaxf(mm, fmax_[w]);
        A.Thdr[0] = mm;
    }
    __syncthreads();
    {   // exactly one item per thread (slice == blockDim)
        int e = my0 + tid;
        float v = (e < N) ? A.t[e] : -A.s[e - N];
        int pi = (e < N) ? (e + N) : (e - N);   // queries sort before equal keys
        int pos = atomicAdd(&pre[t_bin(v)], 1);
        A.vals64[pos] = ((unsigned long long)f_ord(v) << 32) | (unsigned)pi;
    }
}

// ---------- K3: exact in-bin rank, thread/position, u64 keys, 4-wide --------
__global__ __launch_bounds__(128) void k3_rank(Args A) {
    int p = blockIdx.x * 128 + threadIdx.x;
    unsigned long long kp = A.vals64[p];
    int b = (int)(kp >> (32 + BSHIFT));
    int lo = A.binstart[b], hi = A.binstart[b + 1];
    int cnt = 0;
    int q = lo;
    while (q < hi && (q & 3)) cnt += (int)(A.vals64[q++] < kp);
    int bend = q + ((hi - q) & ~3);
    #pragma unroll 2
    for (; q < bend; q += 4) {
        ulonglong2 u0 = *(const ulonglong2*)&A.vals64[q];
        ulonglong2 u1 = *(const ulonglong2*)&A.vals64[q + 2];
        cnt += (int)(u0.x < kp) + (int)(u0.y < kp)
             + (int)(u1.x < kp) + (int)(u1.y < kp);
    }
    while (q < hi) cnt += (int)(A.vals64[q++] < kp);
    int pi = (int)(unsigned)(kp & 0xffffffffu);
    A.tfin[lo + cnt] = ord_f((unsigned)(kp >> 32));
    A.idfin[lo + cnt] = (pi >= N) ? (pi - N) : (pi + N);
}

// ---------- K4: per-chunk (64 sorted items) key-sums, wave per block --------
__global__ __launch_bounds__(64) void k4_sums(Args A) {
    int lane = threadIdx.x;
    int c = blockIdx.x;                         // 384 blocks
    float T = A.Thdr[0];
    float myval = A.tfin[c * 64 + lane];
    int myid = A.idfin[c * 64 + lane];
    float x[64];
    #pragma unroll
    for (int k = 0; k < 64; ++k) {              // 64 independent gathers
        int uid = __shfl(myid, k, 64);
        x[k] = (uid < N) ? A.Wh[(size_t)uid * DOUT + lane] : 0.f;
    }
    float av = 0.f, au = 0.f, svs = 0.f, sus = 0.f;
    #pragma unroll
    for (int k = 0; k < 64; ++k) {
        int uid = __shfl(myid, k, 64);
        if (uid < N) {
            float uval = __shfl(myval, k, 64);
            float wv = expf(0.2f * (uval - T));
            float w2 = wv * wv, w4 = w2 * w2;
            float wu = w4 * wv;                 // exp(uval-T) = wv^5
            av = fmaf(wv, x[k], av); au = fmaf(wu, x[k], au);
            svs += wv; sus += wu;
        }
    }
    A.VU[c * 64 + lane] = make_float2(av, au);
    if (lane == 0) A.sc[c] = make_float2(svs, sus);
}

// ---------- K5: per-wave prefix over chunk sums + sweep; queries emit -------
__global__ __launch_bounds__(64) void k5_apply(Args A) {
    int lane = threadIdx.x;
    int c = blockIdx.x;                         // 384 blocks
    float T = A.Thdr[0];
    // forward-exclusive bases for this chunk + U totals (suffix = total-prefix)
    float bv = 0.f, bu = 0.f, bvs = 0.f, bus = 0.f;
    #pragma unroll 8
    for (int cp = 0; cp < c; ++cp) {
        float2 vu = A.VU[cp * 64 + lane];
        float2 s2 = A.sc[cp];
        bv += vu.x; bu += vu.y; bvs += s2.x; bus += s2.y;
    }
    float tu = bu, tus = bus;
    #pragma unroll 8
    for (int cp = c; cp < NCHUNK; ++cp) {
        float2 vu = A.VU[cp * 64 + lane];
        float2 s2 = A.sc[cp];
        tu += vu.y; tus += s2.y;
    }
    float myval = A.tfin[c * 64 + lane];
    int myid = A.idfin[c * 64 + lane];
    float x[64];
    #pragma unroll
    for (int k = 0; k < 64; ++k) {              // 64 independent gathers
        int uid = __shfl(myid, k, 64);
        x[k] = (uid < N) ? A.Wh[(size_t)uid * DOUT + lane] : 0.f;
    }
    float rv = bv, ru = bu, rvs = bvs, rus = bus;
    #pragma unroll
    for (int k = 0; k < 64; ++k) {
        float uval = __shfl(myval, k, 64);
        int uid = __shfl(myid, k, 64);
        if (uid < N) {                          // key: advance running sums
            float wv = expf(0.2f * (uval - T));
            float w2 = wv * wv, w4 = w2 * w2;
            float wu = w4 * wv;                 // exp(uval-T)
            rv = fmaf(wv, x[k], rv); ru = fmaf(wu, x[k], ru);
            rvs += wv; rus += wu;
        } else {                                // query: emit output row
            int i = uid - N;
            float si = -uval;
            float xx = si + T;
            float mm = fmaxf(xx, 0.2f * xx);
            float cp_ = expf(xx - mm);
            float cn_ = expf(0.2f * xx - mm);
            float num = cn_ * rv + cp_ * (tu - ru);
            float den = cn_ * rvs + cp_ * (tus - rus);
            float r = num / den;
            A.out[(size_t)i * DOUT + lane] = r > 0.f ? r : expm1f(r);
        }
    }
}

extern "C" void kernel_launch(void* const* d_in, const int* in_sizes, int n_in,
                              void* d_out, int out_size, void* d_ws, size_t ws_size,
                              hipStream_t stream) {
    float* ws = (float*)d_ws;
    size_t o = 0;
    Args A;
    A.h = (const float*)d_in[0];
    A.W = (const float*)d_in[1];
    A.a = (const float*)d_in[2];
    A.out = (float*)d_out;
    A.Wh      = ws + o; o += (size_t)N * DOUT;
    A.s       = ws + o; o += N;
    A.t       = ws + o; o += N;
    A.tblkmax = ws + o; o += NCHUNK;            // 384 k1 blocks
    A.Thdr    = ws + o; o += 16;                // keeps o 16B-aligned
    A.vals64  = (unsigned long long*)(ws + o); o += 2 * (size_t)M;
    A.tfin    = ws + o; o += M;
    A.VU      = (float2*)(ws + o); o += 2 * (size_t)NCHUNK * DOUT;
    A.sc      = (float2*)(ws + o); o += 2 * NCHUNK;
    A.idfin    = (int*)(ws + o); o += M;
    A.binstart = (int*)(ws + o); o += NBIN + 1;
    // ~3.9 MB total; no initialization required

    k1_gemm <<<N / 32, 128, 0, stream>>>(A);
    k2_sort <<<24, 1024, 0, stream>>>(A);
    k3_rank <<<M / 128, 128, 0, stream>>>(A);
    k4_sums <<<NCHUNK, 64, 0, stream>>>(A);
    k5_apply<<<NCHUNK, 64, 0, stream>>>(A);
}

// Round 10
// 140.724 us; speedup vs baseline: 1.1062x; 1.1062x over previous
//
#include <hip/hip_runtime.h>

#define N 12288
#define M (2 * N)          // keys (t_j) + queries (-s_i)
#define DIN 128
#define DOUT 64
#define NBIN 8192
#define BSHIFT 19          // 32 - log2(NBIN)
#define NCHUNK 384         // M / 64

// monotone float -> ordered u32 (order-preserving bit transform)
__device__ __forceinline__ unsigned f_ord(float x) {
    unsigned b = __float_as_uint(x);
    return (b & 0x80000000u) ? ~b : (b | 0x80000000u);
}
__device__ __forceinline__ float ord_f(unsigned u) {
    unsigned b = (u & 0x80000000u) ? (u & 0x7FFFFFFFu) : ~u;
    return __uint_as_float(b);
}
__device__ __forceinline__ int t_bin(float x) { return (int)(f_ord(x) >> BSHIFT); }

struct Args {
    const float *h, *W, *a;
    float *Wh, *s, *t, *tblkmax, *Thdr;
    unsigned long long *vals64;     // (ordered(val)<<32)|pi — unique total order
    float *tfin;
    int *idfin, *binstart;
    float2 *VU, *sc;                // per-chunk column/scalar sums {v,u}
    float2 *baseVU, *basesc;        // forward-exclusive prefixes
    float *utot, *utots;            // U totals (suffix = total - prefix)
    float *out;
};

// ---------- K1: Wh = h@W, s, t, per-block max(t) (384 blocks x 128) ---------
__global__ __launch_bounds__(128) void k1_gemm(Args A) {
    __shared__ float4 sm4[3072];               // 48 KB: W 32K + h-tile 16K
    __shared__ float wmax[2];
    int tid = threadIdx.x, wave = tid >> 6, lane = tid & 63, blk = blockIdx.x;
    float4* Ws4 = sm4;                         // W[k][c4]  (2048)
    float4* hs4 = sm4 + 2048;                  // h[r][k4]  (1024: 32 rows)
    const float4* W4 = (const float4*)A.W;
    #pragma unroll
    for (int e = tid; e < 2048; e += 128) Ws4[e] = W4[e];
    int row0 = blk * 32;
    const float4* h4 = (const float4*)(A.h + (size_t)row0 * DIN);
    #pragma unroll
    for (int e = tid; e < 1024; e += 128) hs4[e] = h4[e];
    __syncthreads();
    int c0 = lane & 15, rq = lane >> 4;
    int rbase = wave * 16 + rq * 4;            // 2 waves cover 32 rows
    float4 acc[4];
    #pragma unroll
    for (int rr = 0; rr < 4; ++rr) acc[rr] = make_float4(0.f, 0.f, 0.f, 0.f);
    #pragma unroll 2
    for (int kk = 0; kk < 32; ++kk) {
        float4 w0 = Ws4[(4 * kk + 0) * 16 + c0];
        float4 w1 = Ws4[(4 * kk + 1) * 16 + c0];
        float4 w2 = Ws4[(4 * kk + 2) * 16 + c0];
        float4 w3 = Ws4[(4 * kk + 3) * 16 + c0];
        #pragma unroll
        for (int rr = 0; rr < 4; ++rr) {
            float4 hv = hs4[(rbase + rr) * 32 + kk];
            acc[rr].x = fmaf(hv.x, w0.x, acc[rr].x);
            acc[rr].y = fmaf(hv.x, w0.y, acc[rr].y);
            acc[rr].z = fmaf(hv.x, w0.z, acc[rr].z);
            acc[rr].w = fmaf(hv.x, w0.w, acc[rr].w);
            acc[rr].x = fmaf(hv.y, w1.x, acc[rr].x);
            acc[rr].y = fmaf(hv.y, w1.y, acc[rr].y);
            acc[rr].z = fmaf(hv.y, w1.z, acc[rr].z);
            acc[rr].w = fmaf(hv.y, w1.w, acc[rr].w);
            acc[rr].x = fmaf(hv.z, w2.x, acc[rr].x);
            acc[rr].y = fmaf(hv.z, w2.y, acc[rr].y);
            acc[rr].z = fmaf(hv.z, w2.z, acc[rr].z);
            acc[rr].w = fmaf(hv.z, w2.w, acc[rr].w);
            acc[rr].x = fmaf(hv.w, w3.x, acc[rr].x);
            acc[rr].y = fmaf(hv.w, w3.y, acc[rr].y);
            acc[rr].z = fmaf(hv.w, w3.z, acc[rr].z);
            acc[rr].w = fmaf(hv.w, w3.w, acc[rr].w);
        }
    }
    float4 a1 = ((const float4*)A.a)[c0];
    float4 a2 = ((const float4*)A.a)[16 + c0];
    float tmax = -3.4e38f;
    #pragma unroll
    for (int rr = 0; rr < 4; ++rr) {
        int row = row0 + rbase + rr;
        ((float4*)A.Wh)[(size_t)row * 16 + c0] = acc[rr];
        float sv = acc[rr].x * a1.x + acc[rr].y * a1.y + acc[rr].z * a1.z + acc[rr].w * a1.w;
        float tv = acc[rr].x * a2.x + acc[rr].y * a2.y + acc[rr].z * a2.z + acc[rr].w * a2.w;
        #pragma unroll
        for (int off = 8; off; off >>= 1) {     // reduce over 16-lane group
            sv += __shfl_xor(sv, off, 64);
            tv += __shfl_xor(tv, off, 64);
        }
        if (c0 == 0) { A.s[row] = sv; A.t[row] = tv; }
        tmax = fmaxf(tmax, tv);
    }
    tmax = fmaxf(tmax, __shfl_xor(tmax, 16, 64));
    tmax = fmaxf(tmax, __shfl_xor(tmax, 32, 64));
    if (lane == 0) wmax[wave] = tmax;
    __syncthreads();
    if (tid == 0) A.tblkmax[blk] = fmaxf(wmax[0], wmax[1]);
}

// ---------- K2: LDS hist + pre-hist + scan + T + packed-key scatter ----------
__global__ __launch_bounds__(1024) void k2_sort(Args A) {
    __shared__ int hist[NBIN];                  // 32 KB
    __shared__ int pre[NBIN];                   // 32 KB
    __shared__ int wtot[16];
    __shared__ float fmax_[16];
    int tid = threadIdx.x, lane = tid & 63, wave = tid >> 6, blk = blockIdx.x;
    #pragma unroll
    for (int e = tid; e < NBIN; e += 1024) { hist[e] = 0; pre[e] = 0; }
    __syncthreads();
    #pragma unroll 4
    for (int e = tid; e < M; e += 1024) {
        float v = (e < N) ? A.t[e] : -A.s[e - N];
        atomicAdd(&hist[t_bin(v)], 1);
    }
    int my0 = blk * 1024;
    #pragma unroll 4
    for (int e = tid; e < my0; e += 1024) {
        float v = (e < N) ? A.t[e] : -A.s[e - N];
        atomicAdd(&pre[t_bin(v)], 1);
    }
    __syncthreads();
    int b0 = tid * 8;
    int c8[8]; int sum = 0;
    #pragma unroll
    for (int g = 0; g < 8; ++g) { c8[g] = sum; sum += hist[b0 + g]; }
    int inc = sum;
    #pragma unroll
    for (int off = 1; off < 64; off <<= 1) {
        int nb = __shfl_up(inc, off, 64);
        if (lane >= off) inc += nb;
    }
    if (lane == 63) wtot[wave] = inc;
    __syncthreads();
    int wbase = 0;
    #pragma unroll
    for (int w = 0; w < 16; ++w) wbase += (w < wave) ? wtot[w] : 0;
    int tstart = wbase + inc - sum;
    #pragma unroll
    for (int g = 0; g < 8; ++g) {
        int bs = tstart + c8[g];
        hist[b0 + g] = bs;
        pre[b0 + g] += bs;
        A.binstart[b0 + g] = bs;                // benign duplicate across blocks
    }
    if (tid == 0 && blk == 0) A.binstart[NBIN] = M;
    float m = (tid < 384) ? A.tblkmax[tid] : -3.4e38f;
    #pragma unroll
    for (int off = 32; off; off >>= 1) m = fmaxf(m, __shfl_xor(m, off, 64));
    if (lane == 0) fmax_[wave] = m;
    __syncthreads();
    if (tid == 0) {
        float mm = fmax_[0];
        #pragma unroll
        for (int w = 1; w < 16; ++w) mm = fmaxf(mm, fmax_[w]);
        A.Thdr[0] = mm;
    }
    __syncthreads();
    {   // exactly one item per thread (slice == blockDim)
        int e = my0 + tid;
        float v = (e < N) ? A.t[e] : -A.s[e - N];
        int pi = (e < N) ? (e + N) : (e - N);   // queries sort before equal keys
        int pos = atomicAdd(&pre[t_bin(v)], 1);
        A.vals64[pos] = ((unsigned long long)f_ord(v) << 32) | (unsigned)pi;
    }
}

// ---------- K3: exact in-bin rank, thread/position, u64 keys, 4-wide --------
__global__ __launch_bounds__(128) void k3_rank(Args A) {
    int p = blockIdx.x * 128 + threadIdx.x;
    unsigned long long kp = A.vals64[p];
    int b = (int)(kp >> (32 + BSHIFT));
    int lo = A.binstart[b], hi = A.binstart[b + 1];
    int cnt = 0;
    int q = lo;
    while (q < hi && (q & 3)) cnt += (int)(A.vals64[q++] < kp);
    int bend = q + ((hi - q) & ~3);
    #pragma unroll 2
    for (; q < bend; q += 4) {
        ulonglong2 u0 = *(const ulonglong2*)&A.vals64[q];
        ulonglong2 u1 = *(const ulonglong2*)&A.vals64[q + 2];
        cnt += (int)(u0.x < kp) + (int)(u0.y < kp)
             + (int)(u1.x < kp) + (int)(u1.y < kp);
    }
    while (q < hi) cnt += (int)(A.vals64[q++] < kp);
    int pi = (int)(unsigned)(kp & 0xffffffffu);
    A.tfin[lo + cnt] = ord_f((unsigned)(kp >> 32));
    A.idfin[lo + cnt] = (pi >= N) ? (pi - N) : (pi + N);
}

// ---------- K4: per-chunk (64 sorted items) key-sums (96 blocks x 256) ------
__global__ __launch_bounds__(256) void k4_sums(Args A) {
    int tid = threadIdx.x, wave = tid >> 6, lane = tid & 63;
    int c = blockIdx.x * 4 + wave;              // 384 chunks
    float T = A.Thdr[0];
    float myval = A.tfin[c * 64 + lane];
    int myid = A.idfin[c * 64 + lane];
    float x[64];
    #pragma unroll
    for (int k = 0; k < 64; ++k) {              // 64 independent gathers
        int uid = __shfl(myid, k, 64);
        x[k] = (uid < N) ? A.Wh[(size_t)uid * DOUT + lane] : 0.f;
    }
    float av = 0.f, au = 0.f, svs = 0.f, sus = 0.f;
    #pragma unroll
    for (int k = 0; k < 64; ++k) {
        int uid = __shfl(myid, k, 64);
        if (uid < N) {
            float uval = __shfl(myval, k, 64);
            float wv = expf(0.2f * (uval - T));
            float w2 = wv * wv, w4 = w2 * w2;
            float wu = w4 * wv;                 // exp(uval-T) = wv^5
            av = fmaf(wv, x[k], av); au = fmaf(wu, x[k], au);
            svs += wv; sus += wu;
        }
    }
    A.VU[c * 64 + lane] = make_float2(av, au);
    if (lane == 0) A.sc[c] = make_float2(svs, sus);
}

// ---------- K4b: wave-parallel forward-exclusive scans (65 tasks) ----------
__global__ __launch_bounds__(256) void k4b_scan(Args A) {
    int tid = threadIdx.x, wave = tid >> 6, lane = tid & 63;
    int task = blockIdx.x * 4 + wave;           // 17 blocks -> 68 waves
    if (task >= 65) return;
    const float2* src; float2* dst; int stride, col = 0;
    if (task < 64) { col = task; src = A.VU; dst = A.baseVU; stride = 64; }
    else           { src = A.sc; dst = A.basesc; stride = 1; }
    float bv = 0.f, bu = 0.f;
    for (int c0 = 0; c0 < NCHUNK; c0 += 64) {
        float2 xv = src[(c0 + lane) * stride + col];
        float iv = xv.x, iu = xv.y;
        #pragma unroll
        for (int off = 1; off < 64; off <<= 1) {
            float nv = __shfl_up(iv, off, 64);
            float nu = __shfl_up(iu, off, 64);
            if (lane >= off) { iv += nv; iu += nu; }
        }
        dst[(c0 + lane) * stride + col] = make_float2(bv + iv - xv.x, bu + iu - xv.y);
        bv += __shfl(iv, 63, 64);
        bu += __shfl(iu, 63, 64);
    }
    if (lane == 0) {
        if (task < 64) A.utot[task] = bu;       // U column total
        else           A.utots[0] = bu;         // U scalar total
    }
}

// ---------- K5: sweep with precomputed bases; queries emit output ----------
__global__ __launch_bounds__(256) void k5_apply(Args A) {
    int tid = threadIdx.x, wave = tid >> 6, lane = tid & 63;
    int c = blockIdx.x * 4 + wave;              // 384 chunks
    float T = A.Thdr[0];
    float myval = A.tfin[c * 64 + lane];
    int myid = A.idfin[c * 64 + lane];
    float x[64];
    #pragma unroll
    for (int k = 0; k < 64; ++k) {              // 64 independent gathers
        int uid = __shfl(myid, k, 64);
        x[k] = (uid < N) ? A.Wh[(size_t)uid * DOUT + lane] : 0.f;
    }
    float2 bvu = A.baseVU[c * 64 + lane];
    float2 bsc = A.basesc[c];
    float rv = bvu.x, ru = bvu.y, rvs = bsc.x, rus = bsc.y;
    float tu  = A.utot[lane];
    float tus = A.utots[0];
    #pragma unroll
    for (int k = 0; k < 64; ++k) {
        float uval = __shfl(myval, k, 64);
        int uid = __shfl(myid, k, 64);
        if (uid < N) {                          // key: advance running sums
            float wv = expf(0.2f * (uval - T));
            float w2 = wv * wv, w4 = w2 * w2;
            float wu = w4 * wv;                 // exp(uval-T)
            rv = fmaf(wv, x[k], rv); ru = fmaf(wu, x[k], ru);
            rvs += wv; rus += wu;
        } else {                                // query: emit output row
            int i = uid - N;
            float si = -uval;
            float xx = si + T;
            float mm = fmaxf(xx, 0.2f * xx);
            float cp_ = expf(xx - mm);
            float cn_ = expf(0.2f * xx - mm);
            float num = cn_ * rv + cp_ * (tu - ru);
            float den = cn_ * rvs + cp_ * (tus - rus);
            float r = num / den;
            A.out[(size_t)i * DOUT + lane] = r > 0.f ? r : expm1f(r);
        }
    }
}

extern "C" void kernel_launch(void* const* d_in, const int* in_sizes, int n_in,
                              void* d_out, int out_size, void* d_ws, size_t ws_size,
                              hipStream_t stream) {
    float* ws = (float*)d_ws;
    size_t o = 0;
    Args A;
    A.h = (const float*)d_in[0];
    A.W = (const float*)d_in[1];
    A.a = (const float*)d_in[2];
    A.out = (float*)d_out;
    A.Wh      = ws + o; o += (size_t)N * DOUT;
    A.s       = ws + o; o += N;
    A.t       = ws + o; o += N;
    A.tblkmax = ws + o; o += NCHUNK;            // 384 k1 blocks
    A.Thdr    = ws + o; o += 16;                // keeps o 16B-aligned
    A.vals64  = (unsigned long long*)(ws + o); o += 2 * (size_t)M;
    A.tfin    = ws + o; o += M;
    A.VU      = (float2*)(ws + o); o += 2 * (size_t)NCHUNK * DOUT;
    A.sc      = (float2*)(ws + o); o += 2 * NCHUNK;
    A.baseVU  = (float2*)(ws + o); o += 2 * (size_t)NCHUNK * DOUT;
    A.basesc  = (float2*)(ws + o); o += 2 * NCHUNK;
    A.utot    = ws + o; o += DOUT;
    A.utots   = ws + o; o += 16;
    A.idfin    = (int*)(ws + o); o += M;
    A.binstart = (int*)(ws + o); o += NBIN + 1;
    // ~4.1 MB total; no initialization required

    k1_gemm <<<N / 32, 128, 0, stream>>>(A);
    k2_sort <<<24, 1024, 0, stream>>>(A);
    k3_rank <<<M / 128, 128, 0, stream>>>(A);
    k4_sums <<<NCHUNK / 4, 256, 0, stream>>>(A);
    k4b_scan<<<17, 256, 0, stream>>>(A);
    k5_apply<<<NCHUNK / 4, 256, 0, stream>>>(A);
}

// Round 11
// 131.920 us; speedup vs baseline: 1.1800x; 1.0667x over previous
//
#include <hip/hip_runtime.h>

#define N 12288
#define M (2 * N)          // keys (t_j) + queries (-s_i)
#define DIN 128
#define DOUT 64
#define NBIN 8192
#define BSHIFT 19          // 32 - log2(NBIN)
#define NCHUNK 384         // M / 64

// monotone float -> ordered u32 (order-preserving bit transform)
__device__ __forceinline__ unsigned f_ord(float x) {
    unsigned b = __float_as_uint(x);
    return (b & 0x80000000u) ? ~b : (b | 0x80000000u);
}
__device__ __forceinline__ float ord_f(unsigned u) {
    unsigned b = (u & 0x80000000u) ? (u & 0x7FFFFFFFu) : ~u;
    return __uint_as_float(b);
}
__device__ __forceinline__ int t_bin(float x) { return (int)(f_ord(x) >> BSHIFT); }

struct Args {
    const float *h, *W, *a;
    float *Wh, *s, *t, *tblkmax, *Thdr;
    unsigned long long *vals64;     // (ordered(val)<<32)|pi — unique total order
    float *tfin;
    int *idfin, *binstart;
    float2 *VU, *sc;                // per-chunk column/scalar sums {v,u}
    float2 *baseVU, *basesc;        // forward-exclusive prefixes
    float *utot, *utots;            // U totals (suffix = total - prefix)
    float *out;
};

// ---------- K1: Wh = h@W, s, t, per-block max(t) (384 blocks x 128) ---------
__global__ __launch_bounds__(128) void k1_gemm(Args A) {
    __shared__ float4 sm4[3072];               // 48 KB: W 32K + h-tile 16K
    __shared__ float wmax[2];
    int tid = threadIdx.x, wave = tid >> 6, lane = tid & 63, blk = blockIdx.x;
    float4* Ws4 = sm4;                         // W[k][c4]  (2048)
    float4* hs4 = sm4 + 2048;                  // h[r][k4]  (1024: 32 rows)
    const float4* W4 = (const float4*)A.W;
    #pragma unroll
    for (int e = tid; e < 2048; e += 128) Ws4[e] = W4[e];
    int row0 = blk * 32;
    const float4* h4 = (const float4*)(A.h + (size_t)row0 * DIN);
    #pragma unroll
    for (int e = tid; e < 1024; e += 128) hs4[e] = h4[e];
    __syncthreads();
    int c0 = lane & 15, rq = lane >> 4;
    int rbase = wave * 16 + rq * 4;            // 2 waves cover 32 rows
    float4 acc[4];
    #pragma unroll
    for (int rr = 0; rr < 4; ++rr) acc[rr] = make_float4(0.f, 0.f, 0.f, 0.f);
    #pragma unroll 2
    for (int kk = 0; kk < 32; ++kk) {
        float4 w0 = Ws4[(4 * kk + 0) * 16 + c0];
        float4 w1 = Ws4[(4 * kk + 1) * 16 + c0];
        float4 w2 = Ws4[(4 * kk + 2) * 16 + c0];
        float4 w3 = Ws4[(4 * kk + 3) * 16 + c0];
        #pragma unroll
        for (int rr = 0; rr < 4; ++rr) {
            float4 hv = hs4[(rbase + rr) * 32 + kk];
            acc[rr].x = fmaf(hv.x, w0.x, acc[rr].x);
            acc[rr].y = fmaf(hv.x, w0.y, acc[rr].y);
            acc[rr].z = fmaf(hv.x, w0.z, acc[rr].z);
            acc[rr].w = fmaf(hv.x, w0.w, acc[rr].w);
            acc[rr].x = fmaf(hv.y, w1.x, acc[rr].x);
            acc[rr].y = fmaf(hv.y, w1.y, acc[rr].y);
            acc[rr].z = fmaf(hv.y, w1.z, acc[rr].z);
            acc[rr].w = fmaf(hv.y, w1.w, acc[rr].w);
            acc[rr].x = fmaf(hv.z, w2.x, acc[rr].x);
            acc[rr].y = fmaf(hv.z, w2.y, acc[rr].y);
            acc[rr].z = fmaf(hv.z, w2.z, acc[rr].z);
            acc[rr].w = fmaf(hv.z, w2.w, acc[rr].w);
            acc[rr].x = fmaf(hv.w, w3.x, acc[rr].x);
            acc[rr].y = fmaf(hv.w, w3.y, acc[rr].y);
            acc[rr].z = fmaf(hv.w, w3.z, acc[rr].z);
            acc[rr].w = fmaf(hv.w, w3.w, acc[rr].w);
        }
    }
    float4 a1 = ((const float4*)A.a)[c0];
    float4 a2 = ((const float4*)A.a)[16 + c0];
    float tmax = -3.4e38f;
    #pragma unroll
    for (int rr = 0; rr < 4; ++rr) {
        int row = row0 + rbase + rr;
        ((float4*)A.Wh)[(size_t)row * 16 + c0] = acc[rr];
        float sv = acc[rr].x * a1.x + acc[rr].y * a1.y + acc[rr].z * a1.z + acc[rr].w * a1.w;
        float tv = acc[rr].x * a2.x + acc[rr].y * a2.y + acc[rr].z * a2.z + acc[rr].w * a2.w;
        #pragma unroll
        for (int off = 8; off; off >>= 1) {     // reduce over 16-lane group
            sv += __shfl_xor(sv, off, 64);
            tv += __shfl_xor(tv, off, 64);
        }
        if (c0 == 0) { A.s[row] = sv; A.t[row] = tv; }
        tmax = fmaxf(tmax, tv);
    }
    tmax = fmaxf(tmax, __shfl_xor(tmax, 16, 64));
    tmax = fmaxf(tmax, __shfl_xor(tmax, 32, 64));
    if (lane == 0) wmax[wave] = tmax;
    __syncthreads();
    if (tid == 0) A.tblkmax[blk] = fmaxf(wmax[0], wmax[1]);
}

// ---------- K2: LDS hist + pre-hist + scan + T + packed-key scatter ----------
__global__ __launch_bounds__(1024) void k2_sort(Args A) {
    __shared__ int hist[NBIN];                  // 32 KB
    __shared__ int pre[NBIN];                   // 32 KB
    __shared__ int wtot[16];
    __shared__ float fmax_[16];
    int tid = threadIdx.x, lane = tid & 63, wave = tid >> 6, blk = blockIdx.x;
    #pragma unroll
    for (int e = tid; e < NBIN; e += 1024) { hist[e] = 0; pre[e] = 0; }
    __syncthreads();
    #pragma unroll 4
    for (int e = tid; e < M; e += 1024) {
        float v = (e < N) ? A.t[e] : -A.s[e - N];
        atomicAdd(&hist[t_bin(v)], 1);
    }
    int my0 = blk * 1024;
    #pragma unroll 4
    for (int e = tid; e < my0; e += 1024) {
        float v = (e < N) ? A.t[e] : -A.s[e - N];
        atomicAdd(&pre[t_bin(v)], 1);
    }
    __syncthreads();
    int b0 = tid * 8;
    int c8[8]; int sum = 0;
    #pragma unroll
    for (int g = 0; g < 8; ++g) { c8[g] = sum; sum += hist[b0 + g]; }
    int inc = sum;
    #pragma unroll
    for (int off = 1; off < 64; off <<= 1) {
        int nb = __shfl_up(inc, off, 64);
        if (lane >= off) inc += nb;
    }
    if (lane == 63) wtot[wave] = inc;
    __syncthreads();
    int wbase = 0;
    #pragma unroll
    for (int w = 0; w < 16; ++w) wbase += (w < wave) ? wtot[w] : 0;
    int tstart = wbase + inc - sum;
    #pragma unroll
    for (int g = 0; g < 8; ++g) {
        int bs = tstart + c8[g];
        hist[b0 + g] = bs;
        pre[b0 + g] += bs;
        A.binstart[b0 + g] = bs;                // benign duplicate across blocks
    }
    if (tid == 0 && blk == 0) A.binstart[NBIN] = M;
    float m = (tid < 384) ? A.tblkmax[tid] : -3.4e38f;
    #pragma unroll
    for (int off = 32; off; off >>= 1) m = fmaxf(m, __shfl_xor(m, off, 64));
    if (lane == 0) fmax_[wave] = m;
    __syncthreads();
    if (tid == 0) {
        float mm = fmax_[0];
        #pragma unroll
        for (int w = 1; w < 16; ++w) mm = fmaxf(mm, fmax_[w]);
        A.Thdr[0] = mm;
    }
    __syncthreads();
    {   // exactly one item per thread (slice == blockDim)
        int e = my0 + tid;
        float v = (e < N) ? A.t[e] : -A.s[e - N];
        int pi = (e < N) ? (e + N) : (e - N);   // queries sort before equal keys
        int pos = atomicAdd(&pre[t_bin(v)], 1);
        A.vals64[pos] = ((unsigned long long)f_ord(v) << 32) | (unsigned)pi;
    }
}

// ---------- K3: exact in-bin rank, 4 THREADS per position ----------
// 384 blocks x 256: item = blk*64 + (tid&63), sub = tid>>6 scans one quarter
// of the item's bin; partial counts combined via LDS. 1536 waves = 6/CU.
__global__ __launch_bounds__(256) void k3_rank(Args A) {
    __shared__ int parts[256];
    int tid = threadIdx.x;
    int li = tid & 63, sub = tid >> 6;
    int p = blockIdx.x * 64 + li;
    unsigned long long kp = A.vals64[p];
    int b = (int)(kp >> (32 + BSHIFT));
    int lo = A.binstart[b], hi = A.binstart[b + 1];
    int len = hi - lo;
    int qlen = (len + 3) >> 2;
    int qlo = lo + sub * qlen;
    if (qlo > hi) qlo = hi;
    int qhi = qlo + qlen;
    if (qhi > hi) qhi = hi;
    int cnt = 0;
    int q = qlo;
    while (q < qhi && (q & 3)) cnt += (int)(A.vals64[q++] < kp);
    int bend = q + ((qhi - q) & ~3);
    #pragma unroll 2
    for (; q < bend; q += 4) {
        ulonglong2 u0 = *(const ulonglong2*)&A.vals64[q];
        ulonglong2 u1 = *(const ulonglong2*)&A.vals64[q + 2];
        cnt += (int)(u0.x < kp) + (int)(u0.y < kp)
             + (int)(u1.x < kp) + (int)(u1.y < kp);
    }
    while (q < qhi) cnt += (int)(A.vals64[q++] < kp);
    parts[sub * 64 + li] = cnt;
    __syncthreads();
    if (sub == 0) {
        int tot = parts[li] + parts[64 + li] + parts[128 + li] + parts[192 + li];
        int pi = (int)(unsigned)(kp & 0xffffffffu);
        A.tfin[lo + tot] = ord_f((unsigned)(kp >> 32));
        A.idfin[lo + tot] = (pi >= N) ? (pi - N) : (pi + N);
    }
}

// ---------- K4: per-chunk (64 sorted items) key-sums (96 blocks x 256) ------
__global__ __launch_bounds__(256) void k4_sums(Args A) {
    int tid = threadIdx.x, wave = tid >> 6, lane = tid & 63;
    int c = blockIdx.x * 4 + wave;              // 384 chunks
    float T = A.Thdr[0];
    float myval = A.tfin[c * 64 + lane];
    int myid = A.idfin[c * 64 + lane];
    float x[64];
    #pragma unroll
    for (int k = 0; k < 64; ++k) {              // 64 independent gathers
        int uid = __shfl(myid, k, 64);
        x[k] = (uid < N) ? A.Wh[(size_t)uid * DOUT + lane] : 0.f;
    }
    float av = 0.f, au = 0.f, svs = 0.f, sus = 0.f;
    #pragma unroll
    for (int k = 0; k < 64; ++k) {
        int uid = __shfl(myid, k, 64);
        if (uid < N) {
            float uval = __shfl(myval, k, 64);
            float wv = expf(0.2f * (uval - T));
            float w2 = wv * wv, w4 = w2 * w2;
            float wu = w4 * wv;                 // exp(uval-T) = wv^5
            av = fmaf(wv, x[k], av); au = fmaf(wu, x[k], au);
            svs += wv; sus += wu;
        }
    }
    A.VU[c * 64 + lane] = make_float2(av, au);
    if (lane == 0) A.sc[c] = make_float2(svs, sus);
}

// ---------- K4b: wave-parallel forward-exclusive scans (65 tasks) ----------
__global__ __launch_bounds__(256) void k4b_scan(Args A) {
    int tid = threadIdx.x, wave = tid >> 6, lane = tid & 63;
    int task = blockIdx.x * 4 + wave;           // 17 blocks -> 68 waves
    if (task >= 65) return;
    const float2* src; float2* dst; int stride, col = 0;
    if (task < 64) { col = task; src = A.VU; dst = A.baseVU; stride = 64; }
    else           { src = A.sc; dst = A.basesc; stride = 1; }
    float bv = 0.f, bu = 0.f;
    for (int c0 = 0; c0 < NCHUNK; c0 += 64) {
        float2 xv = src[(c0 + lane) * stride + col];
        float iv = xv.x, iu = xv.y;
        #pragma unroll
        for (int off = 1; off < 64; off <<= 1) {
            float nv = __shfl_up(iv, off, 64);
            float nu = __shfl_up(iu, off, 64);
            if (lane >= off) { iv += nv; iu += nu; }
        }
        dst[(c0 + lane) * stride + col] = make_float2(bv + iv - xv.x, bu + iu - xv.y);
        bv += __shfl(iv, 63, 64);
        bu += __shfl(iu, 63, 64);
    }
    if (lane == 0) {
        if (task < 64) A.utot[task] = bu;       // U column total
        else           A.utots[0] = bu;         // U scalar total
    }
}

// ---------- K5: sweep with precomputed bases; queries emit output ----------
__global__ __launch_bounds__(256) void k5_apply(Args A) {
    int tid = threadIdx.x, wave = tid >> 6, lane = tid & 63;
    int c = blockIdx.x * 4 + wave;              // 384 chunks
    float T = A.Thdr[0];
    float myval = A.tfin[c * 64 + lane];
    int myid = A.idfin[c * 64 + lane];
    float x[64];
    #pragma unroll
    for (int k = 0; k < 64; ++k) {              // 64 independent gathers
        int uid = __shfl(myid, k, 64);
        x[k] = (uid < N) ? A.Wh[(size_t)uid * DOUT + lane] : 0.f;
    }
    float2 bvu = A.baseVU[c * 64 + lane];
    float2 bsc = A.basesc[c];
    float rv = bvu.x, ru = bvu.y, rvs = bsc.x, rus = bsc.y;
    float tu  = A.utot[lane];
    float tus = A.utots[0];
    #pragma unroll
    for (int k = 0; k < 64; ++k) {
        float uval = __shfl(myval, k, 64);
        int uid = __shfl(myid, k, 64);
        if (uid < N) {                          // key: advance running sums
            float wv = expf(0.2f * (uval - T));
            float w2 = wv * wv, w4 = w2 * w2;
            float wu = w4 * wv;                 // exp(uval-T)
            rv = fmaf(wv, x[k], rv); ru = fmaf(wu, x[k], ru);
            rvs += wv; rus += wu;
        } else {                                // query: emit output row
            int i = uid - N;
            float si = -uval;
            float xx = si + T;
            float mm = fmaxf(xx, 0.2f * xx);
            float cp_ = expf(xx - mm);
            float cn_ = expf(0.2f * xx - mm);
            float num = cn_ * rv + cp_ * (tu - ru);
            float den = cn_ * rvs + cp_ * (tus - rus);
            float r = num / den;
            A.out[(size_t)i * DOUT + lane] = r > 0.f ? r : expm1f(r);
        }
    }
}

extern "C" void kernel_launch(void* const* d_in, const int* in_sizes, int n_in,
                              void* d_out, int out_size, void* d_ws, size_t ws_size,
                              hipStream_t stream) {
    float* ws = (float*)d_ws;
    size_t o = 0;
    Args A;
    A.h = (const float*)d_in[0];
    A.W = (const float*)d_in[1];
    A.a = (const float*)d_in[2];
    A.out = (float*)d_out;
    A.Wh      = ws + o; o += (size_t)N * DOUT;
    A.s       = ws + o; o += N;
    A.t       = ws + o; o += N;
    A.tblkmax = ws + o; o += NCHUNK;            // 384 k1 blocks
    A.Thdr    = ws + o; o += 16;                // keeps o 16B-aligned
    A.vals64  = (unsigned long long*)(ws + o); o += 2 * (size_t)M;
    A.tfin    = ws + o; o += M;
    A.VU      = (float2*)(ws + o); o += 2 * (size_t)NCHUNK * DOUT;
    A.sc      = (float2*)(ws + o); o += 2 * NCHUNK;
    A.baseVU  = (float2*)(ws + o); o += 2 * (size_t)NCHUNK * DOUT;
    A.basesc  = (float2*)(ws + o); o += 2 * NCHUNK;
    A.utot    = ws + o; o += DOUT;
    A.utots   = ws + o; o += 16;
    A.idfin    = (int*)(ws + o); o += M;
    A.binstart = (int*)(ws + o); o += NBIN + 1;
    // ~4.1 MB total; no initialization required

    k1_gemm <<<N / 32, 128, 0, stream>>>(A);
    k2_sort <<<24, 1024, 0, stream>>>(A);
    k3_rank <<<M / 64, 256, 0, stream>>>(A);
    k4_sums <<<NCHUNK / 4, 256, 0, stream>>>(A);
    k4b_scan<<<17, 256, 0, stream>>>(A);
    k5_apply<<<NCHUNK / 4, 256, 0, stream>>>(A);
}